// Round 1
// baseline (3735.445 us; speedup 1.0000x reference)
//
#include <hip/hip_runtime.h>

#define B_    8
#define CIN   32
#define COUT  32
#define H_    512
#define W_    512
#define SDIM  512

// 1/sqrt(512), 1/sqrt(32*3*3)
#define MOD_SCALE  0.044194173824159216f
#define CONV_SCALE 0.05892556509887896f

// ---------------------------------------------------------------------------
// Kernel 1: modulation + demodulation. One wave (64 threads) per (b, co).
//   s[b][ci]   = sum_j style[b][j] * mod_w[ci][j] * MOD_SCALE + mod_b[ci]
//   wraw       = CONV_SCALE * weight[co][ci][kh][kw] * s[b][ci]
//   demod      = rsqrt(sum wraw^2 + 1e-8)
//   wmod       = wraw * demod        -> d_ws, layout [B][COUT][CIN*9]
// ---------------------------------------------------------------------------
__global__ __launch_bounds__(64) void modweights_kernel(
    const float* __restrict__ style,
    const float* __restrict__ weight,
    const float* __restrict__ mod_w,
    const float* __restrict__ mod_b,
    float* __restrict__ wmod)
{
    const int b  = blockIdx.x / COUT;
    const int co = blockIdx.x % COUT;
    const int t  = threadIdx.x;

    __shared__ float s_sh[CIN];
    __shared__ float wv[CIN * 9];

    if (t < CIN) {
        const float* st = style + b * SDIM;
        const float* mw = mod_w + t * SDIM;
        float acc = 0.f;
        for (int j = 0; j < SDIM; ++j) acc += st[j] * mw[j];
        s_sh[t] = acc * MOD_SCALE + mod_b[t];
    }
    __syncthreads();

    float ss = 0.f;
    const float* wco = weight + co * CIN * 9;
    for (int i = t; i < CIN * 9; i += 64) {
        float v = CONV_SCALE * wco[i] * s_sh[i / 9];
        wv[i] = v;            // same thread writes & re-reads -> no barrier needed
        ss += v * v;
    }
    // butterfly reduce across the single wave (64 lanes)
    #pragma unroll
    for (int off = 32; off > 0; off >>= 1) ss += __shfl_xor(ss, off);

    const float dem = rsqrtf(ss + 1e-8f);
    float* o = wmod + (b * COUT + co) * CIN * 9;
    for (int i = t; i < CIN * 9; i += 64) o[i] = wv[i] * dem;
}

// ---------------------------------------------------------------------------
// Kernel 2: direct conv. Block = one output row of one (b, co).
// 128 threads x 4 pixels each (float4 stores). Weights in LDS (broadcast reads).
// ---------------------------------------------------------------------------
__global__ __launch_bounds__(128) void conv_kernel(
    const float* __restrict__ x,
    const float* __restrict__ wmod,
    float* __restrict__ out)
{
    const int h  = blockIdx.x;
    const int co = blockIdx.y;
    const int b  = blockIdx.z;
    const int t  = threadIdx.x;

    __shared__ float wsh[CIN * 9];
    {
        const float* wsrc = wmod + (b * COUT + co) * CIN * 9;
        for (int i = t; i < CIN * 9; i += 128) wsh[i] = wsrc[i];
    }
    __syncthreads();

    const int w0 = t * 4;
    float a0 = 0.f, a1 = 0.f, a2 = 0.f, a3 = 0.f;

    const float* xb = x + (size_t)b * CIN * H_ * W_;

    for (int ci = 0; ci < CIN; ++ci) {
        const float* xc = xb + (size_t)ci * H_ * W_;
        const float* wc = wsh + ci * 9;
        #pragma unroll
        for (int kh = 0; kh < 3; ++kh) {
            const int ih = h + kh - 1;            // uniform across block
            if (ih < 0 || ih >= H_) continue;
            const float* r = xc + (size_t)ih * W_ + w0;

            const float  xm1 = (w0 > 0)      ? r[-1] : 0.f;
            const float4 v   = *(const float4*)r;     // aligned
            const float  xp4 = (w0 + 4 < W_) ? r[4]  : 0.f;

            const float wk0 = wc[kh * 3 + 0];
            const float wk1 = wc[kh * 3 + 1];
            const float wk2 = wc[kh * 3 + 2];

            a0 += xm1 * wk0 + v.x * wk1 + v.y * wk2;
            a1 += v.x * wk0 + v.y * wk1 + v.z * wk2;
            a2 += v.y * wk0 + v.z * wk1 + v.w * wk2;
            a3 += v.z * wk0 + v.w * wk1 + xp4 * wk2;
        }
    }

    float* o = out + ((size_t)(b * COUT + co) * H_ + h) * W_ + w0;
    *(float4*)o = make_float4(a0, a1, a2, a3);
}

// ---------------------------------------------------------------------------
extern "C" void kernel_launch(void* const* d_in, const int* in_sizes, int n_in,
                              void* d_out, int out_size, void* d_ws, size_t ws_size,
                              hipStream_t stream)
{
    const float* x      = (const float*)d_in[0];
    const float* style  = (const float*)d_in[1];
    const float* weight = (const float*)d_in[2];
    const float* mod_w  = (const float*)d_in[3];
    const float* mod_b  = (const float*)d_in[4];
    float* out  = (float*)d_out;
    float* wmod = (float*)d_ws;   // B*COUT*CIN*9 floats = 294912 bytes

    modweights_kernel<<<B_ * COUT, 64, 0, stream>>>(style, weight, mod_w, mod_b, wmod);

    dim3 grid(H_, COUT, B_);
    conv_kernel<<<grid, 128, 0, stream>>>(x, wmod, out);
}

// Round 2
// 910.634 us; speedup vs baseline: 4.1020x; 4.1020x over previous
//
#include <hip/hip_runtime.h>

#define B_    8
#define CIN   32
#define COUT  32
#define H_    512
#define W_    512
#define SDIM  512

#define COT   16          // co-tile per block

// 1/sqrt(512), 1/sqrt(32*3*3)
#define MOD_SCALE  0.044194173824159216f
#define CONV_SCALE 0.05892556509887896f

// ---------------------------------------------------------------------------
// Kernel 1: modulation + demodulation. One wave (64 threads) per (b, co).
// wmod layout: [B][COUT][CIN*9]
// ---------------------------------------------------------------------------
__global__ __launch_bounds__(64) void modweights_kernel(
    const float* __restrict__ style,
    const float* __restrict__ weight,
    const float* __restrict__ mod_w,
    const float* __restrict__ mod_b,
    float* __restrict__ wmod)
{
    const int b  = blockIdx.x / COUT;
    const int co = blockIdx.x % COUT;
    const int t  = threadIdx.x;

    __shared__ float s_sh[CIN];
    __shared__ float wv[CIN * 9];

    if (t < CIN) {
        const float* st = style + b * SDIM;
        const float* mw = mod_w + t * SDIM;
        float acc = 0.f;
        for (int j = 0; j < SDIM; ++j) acc += st[j] * mw[j];
        s_sh[t] = acc * MOD_SCALE + mod_b[t];
    }
    __syncthreads();

    float ss = 0.f;
    const float* wco = weight + co * CIN * 9;
    for (int i = t; i < CIN * 9; i += 64) {
        float v = CONV_SCALE * wco[i] * s_sh[i / 9];
        wv[i] = v;
        ss += v * v;
    }
    #pragma unroll
    for (int off = 32; off > 0; off >>= 1) ss += __shfl_xor(ss, off);

    const float dem = rsqrtf(ss + 1e-8f);
    float* o = wmod + (b * COUT + co) * CIN * 9;
    for (int i = t; i < CIN * 9; i += 64) o[i] = wv[i] * dem;
}

// ---------------------------------------------------------------------------
// Kernel 2: direct conv, register-blocked over COT=16 output channels.
// Block = 256 threads: 2 output rows x (128 threads x 4 px).
// Each thread: acc[16][4]; x loaded once per (ci,kh), halo via shfl.
// ---------------------------------------------------------------------------
__global__ __launch_bounds__(256) void conv_kernel(
    const float* __restrict__ x,
    const float* __restrict__ wmod,
    float* __restrict__ out)
{
    const int t    = threadIdx.x;
    const int row  = t >> 7;          // 0 or 1 (waves 0,1 -> row 0; waves 2,3 -> row 1)
    const int tr   = t & 127;
    const int lane = t & 63;
    const int w0   = tr * 4;

    const int h   = blockIdx.x * 2 + row;
    const int co0 = blockIdx.y * COT;
    const int b   = blockIdx.z;

    // weights for this (b, co-tile): [COT][CIN][9] = 18 KB
    __shared__ float wsh[COT * CIN * 9];
    {
        const float* wsrc = wmod + ((size_t)(b * COUT + co0)) * CIN * 9;
        for (int i = t; i < COT * CIN * 9; i += 256) wsh[i] = wsrc[i];
    }
    __syncthreads();

    float acc[COT][4];
    #pragma unroll
    for (int c = 0; c < COT; ++c)
        { acc[c][0] = 0.f; acc[c][1] = 0.f; acc[c][2] = 0.f; acc[c][3] = 0.f; }

    const float* xb = x + (size_t)b * CIN * H_ * W_;

    #pragma unroll 1
    for (int ci = 0; ci < CIN; ++ci) {
        const float* xc = xb + (size_t)ci * H_ * W_;

        float xv[3][6];   // [kh][xm1, x0..x3, xp4]
        #pragma unroll
        for (int kh = 0; kh < 3; ++kh) {
            const int ih = h + kh - 1;                  // wave-uniform
            if (ih >= 0 && ih < H_) {
                const float* r = xc + (size_t)ih * W_ + w0;
                const float4 v = *(const float4*)r;
                float xm1 = __shfl_up(v.w, 1);
                float xp4 = __shfl_down(v.x, 1);
                if (lane == 0)  xm1 = (w0 > 0)       ? r[-1] : 0.f;
                if (lane == 63) xp4 = (w0 + 4 < W_)  ? r[4]  : 0.f;
                xv[kh][0] = xm1; xv[kh][1] = v.x; xv[kh][2] = v.y;
                xv[kh][3] = v.z; xv[kh][4] = v.w; xv[kh][5] = xp4;
            } else {
                #pragma unroll
                for (int j = 0; j < 6; ++j) xv[kh][j] = 0.f;
            }
        }

        #pragma unroll
        for (int c = 0; c < COT; ++c) {
            const float* wc = wsh + (c * CIN + ci) * 9;   // broadcast LDS reads
            float wk[9];
            #pragma unroll
            for (int j = 0; j < 9; ++j) wk[j] = wc[j];

            #pragma unroll
            for (int kh = 0; kh < 3; ++kh) {
                const float* xr = xv[kh];
                const float k0 = wk[kh * 3 + 0];
                const float k1 = wk[kh * 3 + 1];
                const float k2 = wk[kh * 3 + 2];
                acc[c][0] += xr[0] * k0 + xr[1] * k1 + xr[2] * k2;
                acc[c][1] += xr[1] * k0 + xr[2] * k1 + xr[3] * k2;
                acc[c][2] += xr[2] * k0 + xr[3] * k1 + xr[4] * k2;
                acc[c][3] += xr[3] * k0 + xr[4] * k1 + xr[5] * k2;
            }
        }
    }

    #pragma unroll
    for (int c = 0; c < COT; ++c) {
        float* o = out + ((size_t)((b * COUT) + co0 + c) * H_ + h) * W_ + w0;
        *(float4*)o = make_float4(acc[c][0], acc[c][1], acc[c][2], acc[c][3]);
    }
}

// ---------------------------------------------------------------------------
extern "C" void kernel_launch(void* const* d_in, const int* in_sizes, int n_in,
                              void* d_out, int out_size, void* d_ws, size_t ws_size,
                              hipStream_t stream)
{
    const float* x      = (const float*)d_in[0];
    const float* style  = (const float*)d_in[1];
    const float* weight = (const float*)d_in[2];
    const float* mod_w  = (const float*)d_in[3];
    const float* mod_b  = (const float*)d_in[4];
    float* out  = (float*)d_out;
    float* wmod = (float*)d_ws;   // B*COUT*CIN*9 floats

    modweights_kernel<<<B_ * COUT, 64, 0, stream>>>(style, weight, mod_w, mod_b, wmod);

    dim3 grid(H_ / 2, COUT / COT, B_);
    conv_kernel<<<grid, 256, 0, stream>>>(x, wmod, out);
}